// Round 8
// baseline (465.713 us; speedup 1.0000x reference)
//
#include <hip/hip_runtime.h>
#include <math.h>

#define AGENTS 400
#define BATCH  64
#define IDIM   50
#define HDIM   192
#define ODIM   3
#define ADIMM  128
#define NHEADS 8
#define HEADD  16
#define LN_EPS 1e-5f

#define PA   200  // activation LDS pitch in bf16 (400 B rows, 16B-aligned)
#define POUT 136  // o LDS pitch in bf16 (272 B rows, 16B-aligned)

typedef __bf16 bf16x8 __attribute__((ext_vector_type(8)));
typedef float  f32x4  __attribute__((ext_vector_type(4)));

__device__ __forceinline__ float gelu_exact(float x) {
    return 0.5f * x * (1.0f + erff(x * 0.70710678118654752f));
}

__device__ __forceinline__ unsigned pack_bf16x2(float a, float b) {
    unsigned short ua = __builtin_bit_cast(unsigned short, (__bf16)a);
    unsigned short ub = __builtin_bit_cast(unsigned short, (__bf16)b);
    return (unsigned)ua | ((unsigned)ub << 16);
}

// ---------------------------------------------------------------------------
// Barrier-free GEMM pass over K (NC chunks of 32), B built straight from
// global fp32 into register fragments, double-buffered one chunk ahead.
// NT=2 keeps arch-VGPR usage ~70 (buf 32 + bfr 8 + frags/addr) so nothing
// spills alongside the 4*NRG*NT AGPR accumulators.
// ---------------------------------------------------------------------------
template<int NC, int KD, int NT, int NRG, int LDW, int PITCH>
__device__ __forceinline__ void gemm_bpass(f32x4 (&acc)[NRG][NT],
                                           const float* const* wptr,
                                           const __bf16* Asrc, int lane)
{
    const int r = lane & 15, g = lane >> 4;
    float buf[2][NT * 8];

    #pragma unroll
    for (int t = 0; t < NT; t++)
        #pragma unroll
        for (int j = 0; j < 8; j++) {
            int k = g * 8 + j;
            buf[0][t * 8 + j] = (k < KD) ? wptr[t][k * LDW + r] : 0.f;
        }

    #pragma unroll
    for (int c = 0; c < NC; c++) {
        const int cur = c & 1, nxt = cur ^ 1;
        if (c + 1 < NC) {
            #pragma unroll
            for (int t = 0; t < NT; t++)
                #pragma unroll
                for (int j = 0; j < 8; j++) {
                    int k = (c + 1) * 32 + g * 8 + j;
                    buf[nxt][t * 8 + j] = (k < KD) ? wptr[t][k * LDW + r] : 0.f;
                }
        }
        bf16x8 bfr[NT];
        #pragma unroll
        for (int t = 0; t < NT; t++)
            #pragma unroll
            for (int j = 0; j < 8; j++)
                bfr[t][j] = (__bf16)buf[cur][t * 8 + j];
        #pragma unroll
        for (int rg = 0; rg < NRG; rg++) {
            bf16x8 af = *(const bf16x8*)&Asrc[(16 * rg + r) * PITCH + c * 32 + g * 8];
            #pragma unroll
            for (int t = 0; t < NT; t++)
                acc[rg][t] = __builtin_amdgcn_mfma_f32_16x16x32_bf16(af, bfr[t], acc[rg][t], 0, 0, 0);
        }
    }
}

// ---------------------------------------------------------------------------
// Kernel A: per-agent MLP on MFMA.  One block (6 waves, 384 thr) per agent.
// Wave owns cols [32w,32w+32), all 64 rows.  Ping-pong As<->Bs keeps one acc
// array live per pass.  (384,3): ~168 VGPR/wave budget vs ~102 used.
// ---------------------------------------------------------------------------
__global__ __launch_bounds__(384, 3) void mlp_kernel(
    const float* __restrict__ x,
    const float* __restrict__ ln_in_g, const float* __restrict__ ln_in_b,
    const float* __restrict__ W1, const float* __restrict__ b1,
    const float* __restrict__ Ws1, const float* __restrict__ bs1,
    const float* __restrict__ W2, const float* __restrict__ b2,
    const float* __restrict__ Ws2, const float* __restrict__ bs2,
    const float* __restrict__ W3, const float* __restrict__ b3,
    const float* __restrict__ ln_h_g, const float* __restrict__ ln_h_b,
    float* __restrict__ h3out)
{
    const int a    = blockIdx.x;
    const int tid  = threadIdx.x;
    const int wave = tid >> 6, lane = tid & 63;
    const int r = lane & 15, g = lane >> 4;
    const int n0 = 32 * wave;

    __shared__ __align__(16) __bf16 As[64 * PA];   // 25.6 KB
    __shared__ __align__(16) __bf16 Bs[64 * PA];   // 25.6 KB
    __shared__ float mu_s[64], rs_s[64];

    // ---- input LN: stats on raw x rows (shared), per-agent affine ----
    if (tid < 256) {
        int rr = tid >> 2, l = tid & 3;
        float s = 0.f, ss = 0.f;
        for (int k = l; k < IDIM; k += 4) { float v = x[rr * IDIM + k]; s += v; ss += v * v; }
        s  += __shfl_down(s, 2, 4);  s  += __shfl_down(s, 1, 4);
        ss += __shfl_down(ss, 2, 4); ss += __shfl_down(ss, 1, 4);
        if (l == 0) {
            float mu = s * (1.0f / IDIM);
            float var = ss * (1.0f / IDIM) - mu * mu;
            mu_s[rr] = mu;
            rs_s[rr] = rsqrtf(var + LN_EPS);
        }
    }
    __syncthreads();
    for (int sidx = tid; sidx < 64 * 64; sidx += 384) {
        int rr = sidx >> 6, k = sidx & 63;
        float v = 0.f;
        if (k < IDIM)
            v = (x[rr * IDIM + k] - mu_s[rr]) * rs_s[rr] * ln_in_g[a * IDIM + k] + ln_in_b[a * IDIM + k];
        As[rr * PA + k] = (__bf16)v;   // zero-pad k in [IDIM,64)
    }
    __syncthreads();

    // ======== stage 1: Bs = h1 = gelu(xn*W1+b1) + xn*Ws1+bs1  (As -> Bs) ===
    {
        const float* W1p  = W1  + (size_t)a * IDIM * HDIM;
        const float* Ws1p = Ws1 + (size_t)a * IDIM * HDIM;
        {   // pass A: gelu part
            const float* wA[2] = { W1p + n0, W1p + n0 + 16 };
            f32x4 acc[4][2];
            #pragma unroll
            for (int i = 0; i < 4; i++)
                #pragma unroll
                for (int t = 0; t < 2; t++) acc[i][t] = (f32x4)0.f;
            gemm_bpass<2, IDIM, 2, 4, HDIM, PA>(acc, wA, As, lane);
            #pragma unroll
            for (int t = 0; t < 2; t++) {
                int col = n0 + 16 * t + r;
                float bb  = b1[a * HDIM + col];
                float bbs = bs1[a * HDIM + col];
                #pragma unroll
                for (int rg = 0; rg < 4; rg++)
                    #pragma unroll
                    for (int i = 0; i < 4; i++) {
                        int row = 16 * rg + 4 * g + i;
                        Bs[row * PA + col] = (__bf16)(gelu_exact(acc[rg][t][i] + bb) + bbs);
                    }
            }
        }
        {   // pass B: skip part, RMW into Bs (wave-private cols)
            const float* wB[2] = { Ws1p + n0, Ws1p + n0 + 16 };
            f32x4 acc[4][2];
            #pragma unroll
            for (int i = 0; i < 4; i++)
                #pragma unroll
                for (int t = 0; t < 2; t++) acc[i][t] = (f32x4)0.f;
            gemm_bpass<2, IDIM, 2, 4, HDIM, PA>(acc, wB, As, lane);
            #pragma unroll
            for (int t = 0; t < 2; t++) {
                int col = n0 + 16 * t + r;
                #pragma unroll
                for (int rg = 0; rg < 4; rg++)
                    #pragma unroll
                    for (int i = 0; i < 4; i++) {
                        int row = 16 * rg + 4 * g + i;
                        Bs[row * PA + col] = (__bf16)((float)Bs[row * PA + col] + acc[rg][t][i]);
                    }
            }
        }
        __syncthreads();
    }

    // ======== stage 2: As = h2 = gelu(h1*W2+b2) + h1*Ws2+bs2  (Bs -> As) ===
    {
        const float* W2p  = W2  + (size_t)a * HDIM * HDIM;
        const float* Ws2p = Ws2 + (size_t)a * HDIM * HDIM;
        {
            const float* wA[2] = { W2p + n0, W2p + n0 + 16 };
            f32x4 acc[4][2];
            #pragma unroll
            for (int i = 0; i < 4; i++)
                #pragma unroll
                for (int t = 0; t < 2; t++) acc[i][t] = (f32x4)0.f;
            gemm_bpass<6, HDIM, 2, 4, HDIM, PA>(acc, wA, Bs, lane);
            #pragma unroll
            for (int t = 0; t < 2; t++) {
                int col = n0 + 16 * t + r;
                float bb  = b2[a * HDIM + col];
                float bbs = bs2[a * HDIM + col];
                #pragma unroll
                for (int rg = 0; rg < 4; rg++)
                    #pragma unroll
                    for (int i = 0; i < 4; i++) {
                        int row = 16 * rg + 4 * g + i;
                        As[row * PA + col] = (__bf16)(gelu_exact(acc[rg][t][i] + bb) + bbs);
                    }
            }
        }
        {
            const float* wB[2] = { Ws2p + n0, Ws2p + n0 + 16 };
            f32x4 acc[4][2];
            #pragma unroll
            for (int i = 0; i < 4; i++)
                #pragma unroll
                for (int t = 0; t < 2; t++) acc[i][t] = (f32x4)0.f;
            gemm_bpass<6, HDIM, 2, 4, HDIM, PA>(acc, wB, Bs, lane);
            #pragma unroll
            for (int t = 0; t < 2; t++) {
                int col = n0 + 16 * t + r;
                #pragma unroll
                for (int rg = 0; rg < 4; rg++)
                    #pragma unroll
                    for (int i = 0; i < 4; i++) {
                        int row = 16 * rg + 4 * g + i;
                        As[row * PA + col] = (__bf16)((float)As[row * PA + col] + acc[rg][t][i]);
                    }
            }
        }
        __syncthreads();
    }

    // ======== stage 3: Bs = h2 + h2*W3 + b3  (As -> Bs), then LN ==========
    {
        const float* W3p = W3 + (size_t)a * HDIM * HDIM;
        const float* wA[2] = { W3p + n0, W3p + n0 + 16 };
        f32x4 acc[4][2];
        #pragma unroll
        for (int i = 0; i < 4; i++)
            #pragma unroll
            for (int t = 0; t < 2; t++) acc[i][t] = (f32x4)0.f;
        gemm_bpass<6, HDIM, 2, 4, HDIM, PA>(acc, wA, As, lane);
        #pragma unroll
        for (int t = 0; t < 2; t++) {
            int col = n0 + 16 * t + r;
            float bb = b3[a * HDIM + col];
            #pragma unroll
            for (int rg = 0; rg < 4; rg++)
                #pragma unroll
                for (int i = 0; i < 4; i++) {
                    int row = 16 * rg + 4 * g + i;
                    Bs[row * PA + col] = (__bf16)((float)As[row * PA + col] + acc[rg][t][i] + bb);
                }
        }
        __syncthreads();
    }

    if (tid < 256) {
        int rr = tid >> 2, l = tid & 3;
        float s = 0.f, ss = 0.f;
        for (int k = l; k < HDIM; k += 4) { float v = (float)Bs[rr * PA + k]; s += v; ss += v * v; }
        s  += __shfl_down(s, 2, 4);  s  += __shfl_down(s, 1, 4);
        ss += __shfl_down(ss, 2, 4); ss += __shfl_down(ss, 1, 4);
        if (l == 0) {
            float mu = s * (1.0f / HDIM);
            float var = ss * (1.0f / HDIM) - mu * mu;
            mu_s[rr] = mu;
            rs_s[rr] = rsqrtf(var + LN_EPS);
        }
    }
    __syncthreads();
    for (int sidx = tid; sidx < 64 * HDIM; sidx += 384) {
        int rr = sidx / HDIM, c = sidx - rr * HDIM;
        float v = ((float)Bs[rr * PA + c] - mu_s[rr]) * rs_s[rr] * ln_h_g[a * HDIM + c] + ln_h_b[a * HDIM + c];
        h3out[((size_t)a * BATCH + rr) * HDIM + c] = v;
    }
}

// ---------------------------------------------------------------------------
// Kernel B: y = LN(h3, shared affine); fused Q|K|V GEMM on MFMA.
// One block (6 waves, 384 thr) per agent; 2 passes x 32 cols of the 384-wide
// concat per wave.
// ---------------------------------------------------------------------------
__global__ __launch_bounds__(384, 3) void qkv_kernel(
    const float* __restrict__ h3,
    const float* __restrict__ aln_g, const float* __restrict__ aln_b,
    const float* __restrict__ Wq, const float* __restrict__ bq,
    const float* __restrict__ Wk, const float* __restrict__ bk,
    const float* __restrict__ Wv, const float* __restrict__ bv,
    float* __restrict__ qT, float* __restrict__ kT, float* __restrict__ vT)
{
    const int a    = blockIdx.x;
    const int tid  = threadIdx.x;
    const int wave = tid >> 6, lane = tid & 63;
    const int r = lane & 15, g = lane >> 4;

    __shared__ __align__(16) __bf16 ys[64 * PA];
    __shared__ float mu_s[64], rs_s[64];

    if (tid < 256) {
        int rr = tid >> 2, l = tid & 3;
        const float* hp = h3 + ((size_t)a * BATCH + rr) * HDIM;
        float s = 0.f, ss = 0.f;
        for (int k = l; k < HDIM; k += 4) { float v = hp[k]; s += v; ss += v * v; }
        s  += __shfl_down(s, 2, 4);  s  += __shfl_down(s, 1, 4);
        ss += __shfl_down(ss, 2, 4); ss += __shfl_down(ss, 1, 4);
        if (l == 0) {
            float mu = s * (1.0f / HDIM);
            float var = ss * (1.0f / HDIM) - mu * mu;
            mu_s[rr] = mu;
            rs_s[rr] = rsqrtf(var + LN_EPS);
        }
    }
    __syncthreads();
    for (int sidx = tid; sidx < 64 * HDIM; sidx += 384) {
        int rr = sidx / HDIM, c = sidx - rr * HDIM;
        float v = (h3[((size_t)a * BATCH + rr) * HDIM + c] - mu_s[rr]) * rs_s[rr] * aln_g[c] + aln_b[c];
        ys[rr * PA + c] = (__bf16)v;
    }
    __syncthreads();

    #pragma unroll
    for (int p = 0; p < 2; p++) {
        const int nb = 192 * p + 32 * wave;
        const float* wA[2];
        #pragma unroll
        for (int t = 0; t < 2; t++) {
            int nt = nb + 16 * t;
            const float* base = (nt < 128) ? Wq : (nt < 256) ? Wk : Wv;
            wA[t] = base + (nt & 127);
        }
        f32x4 acc[4][2];
        #pragma unroll
        for (int i = 0; i < 4; i++)
            #pragma unroll
            for (int t = 0; t < 2; t++) acc[i][t] = (f32x4)0.f;
        gemm_bpass<6, HDIM, 2, 4, ADIMM, PA>(acc, wA, ys, lane);

        #pragma unroll
        for (int t = 0; t < 2; t++) {
            int n = nb + 16 * t + r;
            int which = n >> 7, cc = n & 127, hh = cc >> 4, dd = cc & 15;
            const float* bp = (which == 0) ? bq : (which == 1) ? bk : bv;
            float* op = (which == 0) ? qT : (which == 1) ? kT : vT;
            float bb = bp[cc];
            #pragma unroll
            for (int rg = 0; rg < 4; rg++)
                #pragma unroll
                for (int i = 0; i < 4; i++) {
                    int brow = 16 * rg + 4 * g + i;
                    op[(((size_t)brow * NHEADS + hh) * AGENTS + a) * HEADD + dd] = acc[rg][t][i] + bb;
                }
        }
    }
}

// ---------------------------------------------------------------------------
// Kernel C: cross-agent attention on MFMA.  One block (4 waves) per (b,h).
// O written to [agent][batch][ADIMM] layout for coalesced out_kernel reads.
// ---------------------------------------------------------------------------
#define PKA 24    // Ks pitch in bf16
#define PVA 408   // Vt pitch in bf16
#define PPA 232   // Ps pitch in bf16

__global__ __launch_bounds__(256, 2) void attn_kernel(
    const float* __restrict__ qT, const float* __restrict__ kT,
    const float* __restrict__ vT, float* __restrict__ oT)
{
    const int bh   = blockIdx.x;
    const int b    = bh >> 3, h = bh & 7;
    const int tid  = threadIdx.x;
    const int wave = tid >> 6, lane = tid & 63;
    const int r = lane & 15, g = lane >> 4;

    __shared__ __align__(16) __bf16 Ks[AGENTS * PKA];      // 19.2 KB
    __shared__ __align__(16) __bf16 Vt[16 * PVA];          // 13.1 KB
    __shared__ __align__(16) __bf16 Ps[4][16 * PPA];       // 29.7 KB

    const float* kp = kT + (size_t)bh * AGENTS * HEADD;
    const float* vp = vT + (size_t)bh * AGENTS * HEADD;
    for (int idx = tid; idx < AGENTS * HEADD; idx += 256) {
        int a_ = idx >> 4, d = idx & 15;
        Ks[a_ * PKA + d] = (__bf16)kp[idx];
        Vt[d * PVA + a_] = (__bf16)vp[idx];
    }
    __bf16* Pw = Ps[wave];
    for (int z = lane; z < 16 * 16; z += 64)
        Pw[(z >> 4) * PPA + 208 + (z & 15)] = (__bf16)0.f;
    __syncthreads();

    for (int mt = wave; mt < 25; mt += 4) {
        const int m0 = mt * 16;

        bf16x8 aq;
        if (g < 2) {
            const float* qp = qT + ((size_t)bh * AGENTS + m0 + r) * HEADD + g * 8;
            #pragma unroll
            for (int j = 0; j < 8; j++) aq[j] = (__bf16)(qp[j] * 0.25f);
        } else {
            #pragma unroll
            for (int j = 0; j < 8; j++) aq[j] = (__bf16)0.f;
        }

        f32x4 sacc[25];
        #pragma unroll
        for (int t = 0; t < 25; t++) {
            bf16x8 bk_ = *(const bf16x8*)&Ks[(t * 16 + r) * PKA + (g & 1) * 8];
            sacc[t] = __builtin_amdgcn_mfma_f32_16x16x32_bf16(aq, bk_, (f32x4)0.f, 0, 0, 0);
        }

        float lv[4];
        #pragma unroll
        for (int i = 0; i < 4; i++) {
            float m_ = sacc[0][i];
            #pragma unroll
            for (int t = 1; t < 25; t++) m_ = fmaxf(m_, sacc[t][i]);
            #pragma unroll
            for (int off = 8; off; off >>= 1) m_ = fmaxf(m_, __shfl_xor(m_, off, 16));
            float l_ = 0.f;
            #pragma unroll
            for (int t = 0; t < 25; t++) {
                float p = __expf(sacc[t][i] - m_);
                sacc[t][i] = p;
                l_ += p;
            }
            #pragma unroll
            for (int off = 8; off; off >>= 1) l_ += __shfl_xor(l_, off, 16);
            lv[i] = l_;
        }

        f32x4 oacc = (f32x4)0.f;

        #pragma unroll
        for (int t = 0; t < 13; t++)
            #pragma unroll
            for (int i = 0; i < 4; i++)
                Pw[(g * 4 + i) * PPA + t * 16 + r] = (__bf16)sacc[t][i];
        __asm__ volatile("s_waitcnt lgkmcnt(0)" ::: "memory");
        #pragma unroll
        for (int c = 0; c < 7; c++) {
            bf16x8 ap  = *(const bf16x8*)&Pw[r * PPA + c * 32 + g * 8];
            bf16x8 bv_ = *(const bf16x8*)&Vt[r * PVA + c * 32 + g * 8];
            oacc = __builtin_amdgcn_mfma_f32_16x16x32_bf16(ap, bv_, oacc, 0, 0, 0);
        }

        for (int z = lane; z < 16 * 16; z += 64)
            Pw[(z >> 4) * PPA + 192 + (z & 15)] = (__bf16)0.f;
        #pragma unroll
        for (int t = 13; t < 25; t++)
            #pragma unroll
            for (int i = 0; i < 4; i++)
                Pw[(g * 4 + i) * PPA + (t - 13) * 16 + r] = (__bf16)sacc[t][i];
        __asm__ volatile("s_waitcnt lgkmcnt(0)" ::: "memory");
        #pragma unroll
        for (int c = 0; c < 6; c++) {
            bf16x8 ap  = *(const bf16x8*)&Pw[r * PPA + c * 32 + g * 8];
            bf16x8 bv_ = *(const bf16x8*)&Vt[r * PVA + 208 + c * 32 + g * 8];
            oacc = __builtin_amdgcn_mfma_f32_16x16x32_bf16(ap, bv_, oacc, 0, 0, 0);
        }

        #pragma unroll
        for (int i = 0; i < 4; i++)
            oT[((size_t)(m0 + g * 4 + i) * BATCH + b) * ADIMM + h * HEADD + r] = oacc[i] / lv[i];
    }
}

// ---------------------------------------------------------------------------
// Kernel D: attended = h3 + o*Wo + bo (MFMA); logits = attended*Wout[a]+bout.
// One block (6 waves, 384 thr) per agent; head MFMA on waves 0-3.
// ---------------------------------------------------------------------------
__global__ __launch_bounds__(384, 3) void out_kernel(
    const float* __restrict__ h3, const float* __restrict__ oT,
    const float* __restrict__ Wo, const float* __restrict__ bo,
    const float* __restrict__ Wout, const float* __restrict__ bout,
    float* __restrict__ out)
{
    const int a    = blockIdx.x;
    const int tid  = threadIdx.x;
    const int wave = tid >> 6, lane = tid & 63;
    const int r = lane & 15, g = lane >> 4;
    const int n0 = 32 * wave;

    __shared__ __align__(16) __bf16 os[64 * POUT];   // 17.4 KB
    __shared__ __align__(16) __bf16 att[64 * PA];    // 25.6 KB

    for (int idx = tid; idx < 64 * 32; idx += 384) {
        int bb = idx >> 5, q = idx & 31;
        float4 v = ((const float4*)(oT + ((size_t)a * BATCH + bb) * ADIMM))[q];
        unsigned u0 = pack_bf16x2(v.x, v.y);
        unsigned u1 = pack_bf16x2(v.z, v.w);
        *(uint2*)&os[bb * POUT + q * 4] = make_uint2(u0, u1);
    }
    __syncthreads();

    {
        const float* wA[2] = { Wo + n0, Wo + n0 + 16 };
        f32x4 acc[4][2];
        #pragma unroll
        for (int i = 0; i < 4; i++)
            #pragma unroll
            for (int t = 0; t < 2; t++) acc[i][t] = (f32x4)0.f;
        gemm_bpass<4, ADIMM, 2, 4, HDIM, POUT>(acc, wA, os, lane);
        #pragma unroll
        for (int t = 0; t < 2; t++) {
            int col = n0 + 16 * t + r;
            float bb = bo[col];
            #pragma unroll
            for (int rg = 0; rg < 4; rg++)
                #pragma unroll
                for (int i = 0; i < 4; i++) {
                    int row = 16 * rg + 4 * g + i;
                    float v = h3[((size_t)a * BATCH + row) * HDIM + col] + acc[rg][t][i] + bb;
                    att[row * PA + col] = (__bf16)v;
                }
        }
    }
    __syncthreads();

    if (wave < 4) {
        const float* Wp = Wout + (size_t)a * HDIM * ODIM;
        float wb[48];
        #pragma unroll
        for (int c = 0; c < 6; c++)
            #pragma unroll
            for (int j = 0; j < 8; j++) {
                int k = c * 32 + g * 8 + j;
                wb[c * 8 + j] = (r < ODIM) ? Wp[k * ODIM + r] : 0.f;
            }
        f32x4 oacc = (f32x4)0.f;
        #pragma unroll
        for (int c = 0; c < 6; c++) {
            bf16x8 bf;
            #pragma unroll
            for (int j = 0; j < 8; j++) bf[j] = (__bf16)wb[c * 8 + j];
            bf16x8 af = *(const bf16x8*)&att[(16 * wave + r) * PA + c * 32 + g * 8];
            oacc = __builtin_amdgcn_mfma_f32_16x16x32_bf16(af, bf, oacc, 0, 0, 0);
        }
        if (r < ODIM) {
            float bb = bout[a * ODIM + r];
            #pragma unroll
            for (int i = 0; i < 4; i++) {
                int row = 16 * wave + 4 * g + i;
                out[((size_t)a * BATCH + row) * ODIM + r] = oacc[i] + bb;
            }
        }
    }
}

// ---------------------------------------------------------------------------
extern "C" void kernel_launch(void* const* d_in, const int* in_sizes, int n_in,
                              void* d_out, int out_size, void* d_ws, size_t ws_size,
                              hipStream_t stream)
{
    const float* x       = (const float*)d_in[0];
    const float* ln_in_g = (const float*)d_in[1];
    const float* ln_in_b = (const float*)d_in[2];
    const float* W1      = (const float*)d_in[3];
    const float* b1      = (const float*)d_in[4];
    const float* Ws1     = (const float*)d_in[5];
    const float* bs1     = (const float*)d_in[6];
    const float* W2      = (const float*)d_in[7];
    const float* b2      = (const float*)d_in[8];
    const float* Ws2     = (const float*)d_in[9];
    const float* bs2     = (const float*)d_in[10];
    const float* W3      = (const float*)d_in[11];
    const float* b3      = (const float*)d_in[12];
    const float* ln_h_g  = (const float*)d_in[13];
    const float* ln_h_b  = (const float*)d_in[14];
    const float* Wout    = (const float*)d_in[15];
    const float* bout    = (const float*)d_in[16];
    const float* aln_g   = (const float*)d_in[17];
    const float* aln_b   = (const float*)d_in[18];
    const float* Wq      = (const float*)d_in[19];
    const float* bq      = (const float*)d_in[20];
    const float* Wk      = (const float*)d_in[21];
    const float* bk      = (const float*)d_in[22];
    const float* Wv      = (const float*)d_in[23];
    const float* bv      = (const float*)d_in[24];
    const float* Wo      = (const float*)d_in[25];
    const float* bo      = (const float*)d_in[26];
    float* out = (float*)d_out;

    float* ws = (float*)d_ws;
    const size_t H3_SZ = (size_t)AGENTS * BATCH * HDIM;
    const size_t QT_SZ = (size_t)BATCH * NHEADS * AGENTS * HEADD;
    float* h3 = ws;
    float* qT = h3 + H3_SZ;
    float* kT = qT + QT_SZ;
    float* vT = kT + QT_SZ;
    float* oT = vT + QT_SZ;

    mlp_kernel<<<AGENTS, 384, 0, stream>>>(x, ln_in_g, ln_in_b,
                                           W1, b1, Ws1, bs1, W2, b2, Ws2, bs2,
                                           W3, b3, ln_h_g, ln_h_b, h3);
    qkv_kernel<<<AGENTS, 384, 0, stream>>>(h3, aln_g, aln_b,
                                           Wq, bq, Wk, bk, Wv, bv, qT, kT, vT);
    attn_kernel<<<BATCH * NHEADS, 256, 0, stream>>>(qT, kT, vT, oT);
    out_kernel<<<AGENTS, 384, 0, stream>>>(h3, oT, Wo, bo, Wout, bout, out);
}

// Round 9
// 386.420 us; speedup vs baseline: 1.2052x; 1.2052x over previous
//
#include <hip/hip_runtime.h>
#include <math.h>

#define AGENTS 400
#define BATCH  64
#define IDIM   50
#define HDIM   192
#define ODIM   3
#define ADIMM  128
#define NHEADS 8
#define HEADD  16
#define LN_EPS 1e-5f

#define PA   200  // activation LDS pitch in bf16 (400 B rows, 16B-aligned)
#define PWK  40   // weight-chunk LDS pitch in bf16 (80 B rows, 16B-aligned)
#define POUT 136  // o LDS pitch in bf16 (272 B rows, 16B-aligned)

typedef __bf16 bf16x8 __attribute__((ext_vector_type(8)));
typedef float  f32x4  __attribute__((ext_vector_type(4)));

__device__ __forceinline__ float gelu_exact(float x) {
    return 0.5f * x * (1.0f + erff(x * 0.70710678118654752f));
}

__device__ __forceinline__ unsigned pack_bf16x2(float a, float b) {
    unsigned short ua = __builtin_bit_cast(unsigned short, (__bf16)a);
    unsigned short ub = __builtin_bit_cast(unsigned short, (__bf16)b);
    return (unsigned)ua | ((unsigned)ub << 16);
}

// ---------------------------------------------------------------------------
// Block-cooperative staging of one K=32 chunk of W[kd x 192] (fp32, row-major)
// into Wt[n][k] bf16 transposed (pitch PWK), zero-filled for k >= kd.
// 256 threads: 24 coalesced global loads + 12 packed ds_write_b32 each.
// ---------------------------------------------------------------------------
__device__ __forceinline__ void stage_w(__bf16* Wtb, const float* __restrict__ Wg,
                                        int kc, int kd, int wave, int lane)
{
    #pragma unroll
    for (int i = 0; i < 4; i++) {
        int kp = (i << 2) + wave;            // 0..15 (k-pair slot)
        int k0 = kc + (kp << 1);
        #pragma unroll
        for (int j = 0; j < 3; j++) {
            int n = lane + (j << 6);         // 0..191
            float f0 = (k0     < kd) ? Wg[(size_t)k0 * HDIM + n]       : 0.f;
            float f1 = (k0 + 1 < kd) ? Wg[(size_t)(k0 + 1) * HDIM + n] : 0.f;
            *(unsigned*)&Wtb[n * PWK + (kp << 1)] = pack_bf16x2(f0, f1);
        }
    }
}

// one MFMA slot: 3 B-frags from Wt chunk, 4 A-frags from As, 12 MFMAs
__device__ __forceinline__ void slot_mfma(f32x4 (&acc)[4][3], const __bf16* As_,
                                          const __bf16* Wtb, int kofs, int n0, int lane)
{
    const int r = lane & 15, g = lane >> 4;
    bf16x8 bf[3];
    #pragma unroll
    for (int t = 0; t < 3; t++)
        bf[t] = *(const bf16x8*)&Wtb[(n0 + 16 * t + r) * PWK + g * 8];
    #pragma unroll
    for (int rg = 0; rg < 4; rg++) {
        bf16x8 af = *(const bf16x8*)&As_[(16 * rg + r) * PA + kofs + g * 8];
        #pragma unroll
        for (int t = 0; t < 3; t++)
            acc[rg][t] = __builtin_amdgcn_mfma_f32_16x16x32_bf16(af, bf[t], acc[rg][t], 0, 0, 0);
    }
}

// ---------------------------------------------------------------------------
// Kernel A: per-agent MLP.  One block (4 waves) per agent.  Weights streamed
// through double-buffered LDS chunks (stage s+1 staged while s computes);
// dual accumulators (W + Ws) live in AGPRs; activations in-place in As
// (epilogues deferred past a barrier).  (256,2): no spill pressure.
// ---------------------------------------------------------------------------
__global__ __launch_bounds__(256, 2) void mlp_kernel(
    const float* __restrict__ x,
    const float* __restrict__ ln_in_g, const float* __restrict__ ln_in_b,
    const float* __restrict__ W1, const float* __restrict__ b1,
    const float* __restrict__ Ws1, const float* __restrict__ bs1,
    const float* __restrict__ W2, const float* __restrict__ b2,
    const float* __restrict__ Ws2, const float* __restrict__ bs2,
    const float* __restrict__ W3, const float* __restrict__ b3,
    const float* __restrict__ ln_h_g, const float* __restrict__ ln_h_b,
    float* __restrict__ h3out)
{
    const int a    = blockIdx.x;
    const int tid  = threadIdx.x;
    const int wave = tid >> 6, lane = tid & 63;
    const int r = lane & 15, g = lane >> 4;
    const int n0 = 48 * wave;

    __shared__ __align__(16) __bf16 As[64 * PA];         // 25.6 KB
    __shared__ __align__(16) __bf16 Wt[2][192 * PWK];    // 30.7 KB
    __shared__ float mu_s[64], rs_s[64];

    // ---- input LN: stats on raw x rows (shared), per-agent affine ----
    {
        int rr = tid >> 2, l = tid & 3;
        float s = 0.f, ss = 0.f;
        for (int k = l; k < IDIM; k += 4) { float v = x[rr * IDIM + k]; s += v; ss += v * v; }
        s  += __shfl_down(s, 2, 4);  s  += __shfl_down(s, 1, 4);
        ss += __shfl_down(ss, 2, 4); ss += __shfl_down(ss, 1, 4);
        if (l == 0) {
            float mu = s * (1.0f / IDIM);
            float var = ss * (1.0f / IDIM) - mu * mu;
            mu_s[rr] = mu;
            rs_s[rr] = rsqrtf(var + LN_EPS);
        }
    }
    __syncthreads();
    for (int sidx = tid; sidx < 64 * 64; sidx += 256) {
        int rr = sidx >> 6, k = sidx & 63;
        float v = 0.f;
        if (k < IDIM)
            v = (x[rr * IDIM + k] - mu_s[rr]) * rs_s[rr] * ln_in_g[a * IDIM + k] + ln_in_b[a * IDIM + k];
        As[rr * PA + k] = (__bf16)v;   // zero-pad k in [IDIM,64)
    }
    __syncthreads();

    const float* W1p  = W1  + (size_t)a * IDIM * HDIM;
    const float* Ws1p = Ws1 + (size_t)a * IDIM * HDIM;
    const float* W2p  = W2  + (size_t)a * HDIM * HDIM;
    const float* Ws2p = Ws2 + (size_t)a * HDIM * HDIM;
    const float* W3p  = W3  + (size_t)a * HDIM * HDIM;

    // ======== stage 1: h1 = gelu(xn*W1+b1) + xn*Ws1+bs1  (in-place) =======
    {
        f32x4 acc1[4][3], acc2[4][3];
        #pragma unroll
        for (int i = 0; i < 4; i++)
            #pragma unroll
            for (int t = 0; t < 3; t++) { acc1[i][t] = (f32x4)0.f; acc2[i][t] = (f32x4)0.f; }
        stage_w(Wt[0], W1p, 0, IDIM, wave, lane);
        __syncthreads();
        #pragma unroll
        for (int s = 0; s < 4; s++) {            // slots: W1c0, Ws1c0, W1c1, Ws1c1
            if (s + 1 < 4) {
                int ns = s + 1;
                stage_w(Wt[(s + 1) & 1], (ns & 1) ? Ws1p : W1p, (ns >> 1) * 32, IDIM, wave, lane);
            }
            if ((s & 1) == 0) slot_mfma(acc1, As, Wt[s & 1], (s >> 1) * 32, n0, lane);
            else              slot_mfma(acc2, As, Wt[s & 1], (s >> 1) * 32, n0, lane);
            __syncthreads();
        }
        // epilogue (all MFMA reads of As complete): write wave-own cols
        #pragma unroll
        for (int t = 0; t < 3; t++) {
            int col = n0 + 16 * t + r;
            float bb  = b1[a * HDIM + col];
            float bbs = bs1[a * HDIM + col];
            #pragma unroll
            for (int rg = 0; rg < 4; rg++)
                #pragma unroll
                for (int i = 0; i < 4; i++) {
                    int row = 16 * rg + 4 * g + i;
                    As[row * PA + col] = (__bf16)(gelu_exact(acc1[rg][t][i] + bb) + acc2[rg][t][i] + bbs);
                }
        }
        __syncthreads();
    }

    // ======== stage 2: h2 = gelu(h1*W2+b2) + h1*Ws2+bs2  (in-place) =======
    {
        f32x4 acc1[4][3], acc2[4][3];
        #pragma unroll
        for (int i = 0; i < 4; i++)
            #pragma unroll
            for (int t = 0; t < 3; t++) { acc1[i][t] = (f32x4)0.f; acc2[i][t] = (f32x4)0.f; }
        stage_w(Wt[0], W2p, 0, HDIM, wave, lane);
        __syncthreads();
        #pragma unroll
        for (int s = 0; s < 12; s++) {
            if (s + 1 < 12) {
                int ns = s + 1;
                stage_w(Wt[(s + 1) & 1], (ns & 1) ? Ws2p : W2p, (ns >> 1) * 32, HDIM, wave, lane);
            }
            if ((s & 1) == 0) slot_mfma(acc1, As, Wt[s & 1], (s >> 1) * 32, n0, lane);
            else              slot_mfma(acc2, As, Wt[s & 1], (s >> 1) * 32, n0, lane);
            __syncthreads();
        }
        #pragma unroll
        for (int t = 0; t < 3; t++) {
            int col = n0 + 16 * t + r;
            float bb  = b2[a * HDIM + col];
            float bbs = bs2[a * HDIM + col];
            #pragma unroll
            for (int rg = 0; rg < 4; rg++)
                #pragma unroll
                for (int i = 0; i < 4; i++) {
                    int row = 16 * rg + 4 * g + i;
                    As[row * PA + col] = (__bf16)(gelu_exact(acc1[rg][t][i] + bb) + acc2[rg][t][i] + bbs);
                }
        }
        __syncthreads();
    }

    // ======== stage 3: t = h2 + h2*W3 + b3 (in-place), then LN ============
    {
        f32x4 acc[4][3];
        #pragma unroll
        for (int i = 0; i < 4; i++)
            #pragma unroll
            for (int t = 0; t < 3; t++) acc[i][t] = (f32x4)0.f;
        stage_w(Wt[0], W3p, 0, HDIM, wave, lane);
        __syncthreads();
        #pragma unroll
        for (int s = 0; s < 6; s++) {
            if (s + 1 < 6)
                stage_w(Wt[(s + 1) & 1], W3p, (s + 1) * 32, HDIM, wave, lane);
            slot_mfma(acc, As, Wt[s & 1], s * 32, n0, lane);
            __syncthreads();
        }
        #pragma unroll
        for (int t = 0; t < 3; t++) {
            int col = n0 + 16 * t + r;
            float bb = b3[a * HDIM + col];
            #pragma unroll
            for (int rg = 0; rg < 4; rg++)
                #pragma unroll
                for (int i = 0; i < 4; i++) {
                    int row = 16 * rg + 4 * g + i;
                    As[row * PA + col] = (__bf16)((float)As[row * PA + col] + acc[rg][t][i] + bb);
                }
        }
        __syncthreads();
    }

    // ---- hidden LN (per-agent affine) -> h3out ----
    {
        int rr = tid >> 2, l = tid & 3;
        float s = 0.f, ss = 0.f;
        for (int k = l; k < HDIM; k += 4) { float v = (float)As[rr * PA + k]; s += v; ss += v * v; }
        s  += __shfl_down(s, 2, 4);  s  += __shfl_down(s, 1, 4);
        ss += __shfl_down(ss, 2, 4); ss += __shfl_down(ss, 1, 4);
        if (l == 0) {
            float mu = s * (1.0f / HDIM);
            float var = ss * (1.0f / HDIM) - mu * mu;
            mu_s[rr] = mu;
            rs_s[rr] = rsqrtf(var + LN_EPS);
        }
    }
    __syncthreads();
    for (int sidx = tid; sidx < 64 * HDIM; sidx += 256) {
        int rr = sidx / HDIM, c = sidx - rr * HDIM;
        float v = ((float)As[rr * PA + c] - mu_s[rr]) * rs_s[rr] * ln_h_g[a * HDIM + c] + ln_h_b[a * HDIM + c];
        h3out[((size_t)a * BATCH + rr) * HDIM + c] = v;
    }
}

// ---------------------------------------------------------------------------
// Register-staged GEMM pass (for the small shared-weight GEMMs: qkv, out).
// ---------------------------------------------------------------------------
template<int NC, int KD, int NT, int NRG, int LDW, int PITCH>
__device__ __forceinline__ void gemm_bpass(f32x4 (&acc)[NRG][NT],
                                           const float* const* wptr,
                                           const __bf16* Asrc, int lane)
{
    const int r = lane & 15, g = lane >> 4;
    float buf[2][NT * 8];

    #pragma unroll
    for (int t = 0; t < NT; t++)
        #pragma unroll
        for (int j = 0; j < 8; j++) {
            int k = g * 8 + j;
            buf[0][t * 8 + j] = (k < KD) ? wptr[t][k * LDW + r] : 0.f;
        }

    #pragma unroll
    for (int c = 0; c < NC; c++) {
        const int cur = c & 1, nxt = cur ^ 1;
        if (c + 1 < NC) {
            #pragma unroll
            for (int t = 0; t < NT; t++)
                #pragma unroll
                for (int j = 0; j < 8; j++) {
                    int k = (c + 1) * 32 + g * 8 + j;
                    buf[nxt][t * 8 + j] = (k < KD) ? wptr[t][k * LDW + r] : 0.f;
                }
        }
        bf16x8 bfr[NT];
        #pragma unroll
        for (int t = 0; t < NT; t++)
            #pragma unroll
            for (int j = 0; j < 8; j++)
                bfr[t][j] = (__bf16)buf[cur][t * 8 + j];
        #pragma unroll
        for (int rg = 0; rg < NRG; rg++) {
            bf16x8 af = *(const bf16x8*)&Asrc[(16 * rg + r) * PITCH + c * 32 + g * 8];
            #pragma unroll
            for (int t = 0; t < NT; t++)
                acc[rg][t] = __builtin_amdgcn_mfma_f32_16x16x32_bf16(af, bfr[t], acc[rg][t], 0, 0, 0);
        }
    }
}

// ---------------------------------------------------------------------------
// Kernel B: y = LN(h3, shared affine); fused Q|K|V GEMM on MFMA.  (R5 form)
// ---------------------------------------------------------------------------
__global__ __launch_bounds__(256, 2) void qkv_kernel(
    const float* __restrict__ h3,
    const float* __restrict__ aln_g, const float* __restrict__ aln_b,
    const float* __restrict__ Wq, const float* __restrict__ bq,
    const float* __restrict__ Wk, const float* __restrict__ bk,
    const float* __restrict__ Wv, const float* __restrict__ bv,
    float* __restrict__ qT, float* __restrict__ kT, float* __restrict__ vT)
{
    const int a    = blockIdx.x;
    const int tid  = threadIdx.x;
    const int wave = tid >> 6, lane = tid & 63;
    const int r = lane & 15, g = lane >> 4;

    __shared__ __align__(16) __bf16 ys[64 * PA];
    __shared__ float mu_s[64], rs_s[64];

    {
        int rr = tid >> 2, l = tid & 3;
        const float* hp = h3 + ((size_t)a * BATCH + rr) * HDIM;
        float s = 0.f, ss = 0.f;
        for (int k = l; k < HDIM; k += 4) { float v = hp[k]; s += v; ss += v * v; }
        s  += __shfl_down(s, 2, 4);  s  += __shfl_down(s, 1, 4);
        ss += __shfl_down(ss, 2, 4); ss += __shfl_down(ss, 1, 4);
        if (l == 0) {
            float mu = s * (1.0f / HDIM);
            float var = ss * (1.0f / HDIM) - mu * mu;
            mu_s[rr] = mu;
            rs_s[rr] = rsqrtf(var + LN_EPS);
        }
    }
    __syncthreads();
    for (int sidx = tid; sidx < 64 * HDIM; sidx += 256) {
        int rr = sidx / HDIM, c = sidx - rr * HDIM;
        float v = (h3[((size_t)a * BATCH + rr) * HDIM + c] - mu_s[rr]) * rs_s[rr] * aln_g[c] + aln_b[c];
        ys[rr * PA + c] = (__bf16)v;
    }
    __syncthreads();

    #pragma unroll
    for (int p = 0; p < 2; p++) {
        const int nb = 192 * p + 48 * wave;
        const float* wA[3];
        #pragma unroll
        for (int t = 0; t < 3; t++) {
            int nt = nb + 16 * t;
            const float* base = (nt < 128) ? Wq : (nt < 256) ? Wk : Wv;
            wA[t] = base + (nt & 127);
        }
        f32x4 acc[4][3];
        #pragma unroll
        for (int i = 0; i < 4; i++)
            #pragma unroll
            for (int t = 0; t < 3; t++) acc[i][t] = (f32x4)0.f;
        gemm_bpass<6, HDIM, 3, 4, ADIMM, PA>(acc, wA, ys, lane);

        #pragma unroll
        for (int t = 0; t < 3; t++) {
            int n = nb + 16 * t + r;
            int which = n >> 7, cc = n & 127, hh = cc >> 4, dd = cc & 15;
            const float* bp = (which == 0) ? bq : (which == 1) ? bk : bv;
            float* op = (which == 0) ? qT : (which == 1) ? kT : vT;
            float bb = bp[cc];
            #pragma unroll
            for (int rg = 0; rg < 4; rg++)
                #pragma unroll
                for (int i = 0; i < 4; i++) {
                    int brow = 16 * rg + 4 * g + i;
                    op[(((size_t)brow * NHEADS + hh) * AGENTS + a) * HEADD + dd] = acc[rg][t][i] + bb;
                }
        }
    }
}

// ---------------------------------------------------------------------------
// Kernel C: cross-agent attention on MFMA.  One block (4 waves) per (b,h).
// ---------------------------------------------------------------------------
#define PKA 24
#define PVA 408
#define PPA 232

__global__ __launch_bounds__(256, 2) void attn_kernel(
    const float* __restrict__ qT, const float* __restrict__ kT,
    const float* __restrict__ vT, float* __restrict__ oT)
{
    const int bh   = blockIdx.x;
    const int b    = bh >> 3, h = bh & 7;
    const int tid  = threadIdx.x;
    const int wave = tid >> 6, lane = tid & 63;
    const int r = lane & 15, g = lane >> 4;

    __shared__ __align__(16) __bf16 Ks[AGENTS * PKA];
    __shared__ __align__(16) __bf16 Vt[16 * PVA];
    __shared__ __align__(16) __bf16 Ps[4][16 * PPA];

    const float* kp = kT + (size_t)bh * AGENTS * HEADD;
    const float* vp = vT + (size_t)bh * AGENTS * HEADD;
    for (int idx = tid; idx < AGENTS * HEADD; idx += 256) {
        int a_ = idx >> 4, d = idx & 15;
        Ks[a_ * PKA + d] = (__bf16)kp[idx];
        Vt[d * PVA + a_] = (__bf16)vp[idx];
    }
    __bf16* Pw = Ps[wave];
    for (int z = lane; z < 16 * 16; z += 64)
        Pw[(z >> 4) * PPA + 208 + (z & 15)] = (__bf16)0.f;
    __syncthreads();

    for (int mt = wave; mt < 25; mt += 4) {
        const int m0 = mt * 16;

        bf16x8 aq;
        if (g < 2) {
            const float* qp = qT + ((size_t)bh * AGENTS + m0 + r) * HEADD + g * 8;
            #pragma unroll
            for (int j = 0; j < 8; j++) aq[j] = (__bf16)(qp[j] * 0.25f);
        } else {
            #pragma unroll
            for (int j = 0; j < 8; j++) aq[j] = (__bf16)0.f;
        }

        f32x4 sacc[25];
        #pragma unroll
        for (int t = 0; t < 25; t++) {
            bf16x8 bk_ = *(const bf16x8*)&Ks[(t * 16 + r) * PKA + (g & 1) * 8];
            sacc[t] = __builtin_amdgcn_mfma_f32_16x16x32_bf16(aq, bk_, (f32x4)0.f, 0, 0, 0);
        }

        float lv[4];
        #pragma unroll
        for (int i = 0; i < 4; i++) {
            float m_ = sacc[0][i];
            #pragma unroll
            for (int t = 1; t < 25; t++) m_ = fmaxf(m_, sacc[t][i]);
            #pragma unroll
            for (int off = 8; off; off >>= 1) m_ = fmaxf(m_, __shfl_xor(m_, off, 16));
            float l_ = 0.f;
            #pragma unroll
            for (int t = 0; t < 25; t++) {
                float p = __expf(sacc[t][i] - m_);
                sacc[t][i] = p;
                l_ += p;
            }
            #pragma unroll
            for (int off = 8; off; off >>= 1) l_ += __shfl_xor(l_, off, 16);
            lv[i] = l_;
        }

        f32x4 oacc = (f32x4)0.f;

        #pragma unroll
        for (int t = 0; t < 13; t++)
            #pragma unroll
            for (int i = 0; i < 4; i++)
                Pw[(g * 4 + i) * PPA + t * 16 + r] = (__bf16)sacc[t][i];
        __asm__ volatile("s_waitcnt lgkmcnt(0)" ::: "memory");
        #pragma unroll
        for (int c = 0; c < 7; c++) {
            bf16x8 ap  = *(const bf16x8*)&Pw[r * PPA + c * 32 + g * 8];
            bf16x8 bv_ = *(const bf16x8*)&Vt[r * PVA + c * 32 + g * 8];
            oacc = __builtin_amdgcn_mfma_f32_16x16x32_bf16(ap, bv_, oacc, 0, 0, 0);
        }

        for (int z = lane; z < 16 * 16; z += 64)
            Pw[(z >> 4) * PPA + 192 + (z & 15)] = (__bf16)0.f;
        #pragma unroll
        for (int t = 13; t < 25; t++)
            #pragma unroll
            for (int i = 0; i < 4; i++)
                Pw[(g * 4 + i) * PPA + (t - 13) * 16 + r] = (__bf16)sacc[t][i];
        __asm__ volatile("s_waitcnt lgkmcnt(0)" ::: "memory");
        #pragma unroll
        for (int c = 0; c < 6; c++) {
            bf16x8 ap  = *(const bf16x8*)&Pw[r * PPA + c * 32 + g * 8];
            bf16x8 bv_ = *(const bf16x8*)&Vt[r * PVA + 208 + c * 32 + g * 8];
            oacc = __builtin_amdgcn_mfma_f32_16x16x32_bf16(ap, bv_, oacc, 0, 0, 0);
        }

        #pragma unroll
        for (int i = 0; i < 4; i++)
            oT[((size_t)(m0 + g * 4 + i) * BATCH + b) * ADIMM + h * HEADD + r] = oacc[i] / lv[i];
    }
}

// ---------------------------------------------------------------------------
// Kernel D: attended = h3 + o*Wo + bo (MFMA); logits = attended*Wout[a]+bout.
// ---------------------------------------------------------------------------
__global__ __launch_bounds__(256, 2) void out_kernel(
    const float* __restrict__ h3, const float* __restrict__ oT,
    const float* __restrict__ Wo, const float* __restrict__ bo,
    const float* __restrict__ Wout, const float* __restrict__ bout,
    float* __restrict__ out)
{
    const int a    = blockIdx.x;
    const int tid  = threadIdx.x;
    const int wave = tid >> 6, lane = tid & 63;
    const int r = lane & 15, g = lane >> 4;
    const int n0 = 48 * wave;

    __shared__ __align__(16) __bf16 os[64 * POUT];
    __shared__ __align__(16) __bf16 att[64 * PA];

    for (int idx = tid; idx < 64 * 32; idx += 256) {
        int bb = idx >> 5, q = idx & 31;
        float4 v = ((const float4*)(oT + ((size_t)a * BATCH + bb) * ADIMM))[q];
        unsigned u0 = pack_bf16x2(v.x, v.y);
        unsigned u1 = pack_bf16x2(v.z, v.w);
        *(uint2*)&os[bb * POUT + q * 4] = make_uint2(u0, u1);
    }
    __syncthreads();

    {
        const float* wA[3] = { Wo + n0, Wo + n0 + 16, Wo + n0 + 32 };
        f32x4 acc[4][3];
        #pragma unroll
        for (int i = 0; i < 4; i++)
            #pragma unroll
            for (int t = 0; t < 3; t++) acc[i][t] = (f32x4)0.f;
        gemm_bpass<4, ADIMM, 3, 4, HDIM, POUT>(acc, wA, os, lane);
        #pragma unroll
        for (int t = 0; t < 3; t++) {
            int col = n0 + 16 * t + r;
            float bb = bo[col];
            #pragma unroll
            for (int rg = 0; rg < 4; rg++)
                #pragma unroll
                for (int i = 0; i < 4; i++) {
                    int row = 16 * rg + 4 * g + i;
                    float v = h3[((size_t)a * BATCH + row) * HDIM + col] + acc[rg][t][i] + bb;
                    att[row * PA + col] = (__bf16)v;
                }
        }
    }
    __syncthreads();

    {
        const float* Wp = Wout + (size_t)a * HDIM * ODIM;
        float wb[48];
        #pragma unroll
        for (int c = 0; c < 6; c++)
            #pragma unroll
            for (int j = 0; j < 8; j++) {
                int k = c * 32 + g * 8 + j;
                wb[c * 8 + j] = (r < ODIM) ? Wp[k * ODIM + r] : 0.f;
            }
        f32x4 oacc = (f32x4)0.f;
        #pragma unroll
        for (int c = 0; c < 6; c++) {
            bf16x8 bf;
            #pragma unroll
            for (int j = 0; j < 8; j++) bf[j] = (__bf16)wb[c * 8 + j];
            bf16x8 af = *(const bf16x8*)&att[(16 * wave + r) * PA + c * 32 + g * 8];
            oacc = __builtin_amdgcn_mfma_f32_16x16x32_bf16(af, bf, oacc, 0, 0, 0);
        }
        if (r < ODIM) {
            float bb = bout[a * ODIM + r];
            #pragma unroll
            for (int i = 0; i < 4; i++) {
                int row = 16 * wave + 4 * g + i;
                out[((size_t)a * BATCH + row) * ODIM + r] = oacc[i] + bb;
            }
        }
    }
}

// ---------------------------------------------------------------------------
extern "C" void kernel_launch(void* const* d_in, const int* in_sizes, int n_in,
                              void* d_out, int out_size, void* d_ws, size_t ws_size,
                              hipStream_t stream)
{
    const float* x       = (const float*)d_in[0];
    const float* ln_in_g = (const float*)d_in[1];
    const float* ln_in_b = (const float*)d_in[2];
    const float* W1      = (const float*)d_in[3];
    const float* b1      = (const float*)d_in[4];
    const float* Ws1     = (const float*)d_in[5];
    const float* bs1     = (const float*)d_in[6];
    const float* W2      = (const float*)d_in[7];
    const float* b2      = (const float*)d_in[8];
    const float* Ws2     = (const float*)d_in[9];
    const float* bs2     = (const float*)d_in[10];
    const float* W3      = (const float*)d_in[11];
    const float* b3      = (const float*)d_in[12];
    const float* ln_h_g  = (const float*)d_in[13];
    const float* ln_h_b  = (const float*)d_in[14];
    const float* Wout    = (const float*)d_in[15];
    const float* bout    = (const float*)d_in[16];
    const float* aln_g   = (const float*)d_in[17];
    const float* aln_b   = (const float*)d_in[18];
    const float* Wq      = (const float*)d_in[19];
    const float* bq      = (const float*)d_in[20];
    const float* Wk      = (const float*)d_in[21];
    const float* bk      = (const float*)d_in[22];
    const float* Wv      = (const float*)d_in[23];
    const float* bv      = (const float*)d_in[24];
    const float* Wo      = (const float*)d_in[25];
    const float* bo      = (const float*)d_in[26];
    float* out = (float*)d_out;

    float* ws = (float*)d_ws;
    const size_t H3_SZ = (size_t)AGENTS * BATCH * HDIM;
    const size_t QT_SZ = (size_t)BATCH * NHEADS * AGENTS * HEADD;
    float* h3 = ws;
    float* qT = h3 + H3_SZ;
    float* kT = qT + QT_SZ;
    float* vT = kT + QT_SZ;
    float* oT = vT + QT_SZ;

    mlp_kernel<<<AGENTS, 256, 0, stream>>>(x, ln_in_g, ln_in_b,
                                           W1, b1, Ws1, bs1, W2, b2, Ws2, bs2,
                                           W3, b3, ln_h_g, ln_h_b, h3);
    qkv_kernel<<<AGENTS, 256, 0, stream>>>(h3, aln_g, aln_b,
                                           Wq, bq, Wk, bk, Wv, bv, qT, kT, vT);
    attn_kernel<<<BATCH * NHEADS, 256, 0, stream>>>(qT, kT, vT, oT);
    out_kernel<<<AGENTS, 256, 0, stream>>>(h3, oT, Wo, bo, Wout, bout, out);
}